// Round 2
// baseline (341.635 us; speedup 1.0000x reference)
//
#include <hip/hip_runtime.h>
#include <math.h>

// Problem dims (fixed by setup_inputs)
#define N_  8
#define C_  4
#define A_  180
#define R_  180
#define NC  (N_*C_)        // 32
#define AR  (A_*R_)        // 32400
#define CAP 2048           // max peaks per (n,c) — expected ~450, huge margin
#define RG  32             // rows per raster block

typedef unsigned long long u64;
typedef unsigned int u32;

// ws layout (bytes)
#define OFF_MAX  0                      // float maxv[32]        (128 B)
#define OFF_CNT  128                    // u32 cnt[32]           (128 B)
#define OFF_TBL  256                    // float tbl[3*180+4]    (2176 B)
#define OFF_LIST 2432                   // u32 list[32][CAP]     (256 KB)
#define WS_BYTES (OFF_LIST + NC*CAP*4)

// ---------------------------------------------------------------------------
// Kernel A: per-(n,c) global max (blocks 0..31) + trig/rho tables (block 32)
// ---------------------------------------------------------------------------
__global__ __launch_bounds__(256) void precompute_kernel(
    const float* __restrict__ hm,
    const int* __restrict__ Hp, const int* __restrict__ Wp,
    float* __restrict__ maxv, float* __restrict__ tbl) {
  int b = blockIdx.x;
  if (b < NC) {
    const float* p = hm + (size_t)b * AR;
    float m = -INFINITY;
    for (int i = threadIdx.x; i < AR; i += 256) m = fmaxf(m, p[i]);
    for (int off = 32; off; off >>= 1) m = fmaxf(m, __shfl_down(m, off, 64));
    __shared__ float sm[4];
    if ((threadIdx.x & 63) == 0) sm[threadIdx.x >> 6] = m;
    __syncthreads();
    if (threadIdx.x == 0) {
      maxv[b] = fmaxf(fmaxf(sm[0], sm[1]), fmaxf(sm[2], sm[3]));
    }
  } else {
    int t = threadIdx.x;
    int H = Hp[0], W = Wp[0];
    double max_rho = sqrt((double)(W/2)*(double)(W/2) + (double)(H/2)*(double)(H/2));
    float drho = (float)(2.0 * max_rho / (double)(R_ - 1));
    if (t < A_) {
      // theta = f32(a) * f32(pi/A)  — matches jnp.arange(A,f32)*(np.pi/A)
      float theta = __fmul_rn((float)t, (float)(3.14159265358979323846 / (double)A_));
      tbl[t]        = (float)cos((double)theta);   // correctly-rounded f32 cos
      tbl[A_ + t]   = (float)sin((double)theta);
      // r_phys = (f32(r) - 89.5) * f32(delta_rho)
      tbl[2*A_ + t] = __fmul_rn(__fsub_rn((float)t, (float)((R_-1)*0.5)), drho);
    }
    if (t == 0) {
      tbl[3*A_ + 0] = drho;
      tbl[3*A_ + 1] = 1.0f / drho;
      tbl[3*A_ + 2] = (float)((W - 1) * 0.5);   // 127.5
      tbl[3*A_ + 3] = (float)((H - 1) * 0.5);
    }
  }
}

// ---------------------------------------------------------------------------
// Kernel B: peak detection -> compact per-(n,c) list of (a<<8 | r)
// peak := hm > 0.5*max  AND  no 3x3 neighbor strictly greater (== maxpool)
// ---------------------------------------------------------------------------
__global__ __launch_bounds__(256) void peaks_kernel(
    const float* __restrict__ hm, const float* __restrict__ maxv,
    u32* __restrict__ cnt, u32* __restrict__ list) {
  int idx = blockIdx.x * 256 + threadIdx.x;
  if (idx >= NC * AR) return;
  int nc  = idx / AR;
  int rem = idx - nc * AR;
  float val = hm[idx];
  float thr = 0.5f * maxv[nc];
  if (!(val > thr)) return;               // ~98% early-out
  int a = rem / R_;
  int r = rem - a * R_;
  const float* base = hm + (size_t)nc * AR;
  bool peak = true;
  for (int da = -1; da <= 1 && peak; ++da) {
    int aa = a + da;
    if (aa < 0 || aa >= A_) continue;     // SAME pad with -inf
    for (int dr = -1; dr <= 1; ++dr) {
      if (da == 0 && dr == 0) continue;
      int rr = r + dr;
      if (rr < 0 || rr >= R_) continue;
      if (base[aa * R_ + rr] > val) { peak = false; break; }
    }
  }
  if (!peak) return;
  u32 slot = atomicAdd(&cnt[nc], 1u);
  if (slot < CAP) list[(size_t)nc * CAP + slot] = (u32)((a << 8) | r);
}

// ---------------------------------------------------------------------------
// Kernel C: per-peak band rasterization into per-row LDS bitmasks.
// For fixed (peak, row), d(x) = f32(f32(xcv*ct)+yst) - rp is monotone in x
// (f32 rounding is monotone), so the exact-true set is a contiguous interval.
// Conservative window from double math (margin 1e-3 >> 3e-5 f32 error),
// exact f32 test inside it, then one bitmask range-set.
// ---------------------------------------------------------------------------
__global__ __launch_bounds__(256) void raster_kernel(
    const float* __restrict__ mwp,
    const u32* __restrict__ cntg, const u32* __restrict__ listg,
    const float* __restrict__ tbl,
    float* __restrict__ out) {
  __shared__ u64  rowbits[RG][4];
  __shared__ float ctl[A_], stl[A_], rpl[R_];
  __shared__ u32  plist[CAP];
  int nc  = blockIdx.y;
  int rg  = blockIdx.x;            // 0..(256/RG - 1)
  int tid = threadIdx.x;
  int cnt = (int)cntg[nc]; if (cnt > CAP) cnt = CAP;

  for (int i = tid; i < A_; i += 256) {
    ctl[i] = tbl[i]; stl[i] = tbl[A_ + i]; rpl[i] = tbl[2*A_ + i];
  }
  for (int i = tid; i < cnt; i += 256) plist[i] = listg[(size_t)nc * CAP + i];
  if (tid < RG * 4) ((u64*)rowbits)[tid] = 0ull;
  __syncthreads();

  float mw  = mwp[0];
  double t3 = (double)mw + 1.0e-3;   // conservative half-width

  int lr    = tid & (RG - 1);        // local row
  int slice = tid >> 5;              // 0..7 peak slices
  int y     = rg * RG + lr;
  float ycv = __fsub_rn((float)y, 127.5f);

  for (int p = slice; p < cnt; p += 8) {
    u32 pk = plist[p];
    int a = (int)(pk >> 8), r = (int)(pk & 255u);
    float ct = ctl[a], st = stl[a], rp = rpl[r];
    float yst = __fmul_rn(ycv, st);
    double ctd = (double)ct;
    double t   = (double)rp - (double)yst;
    double b0  = (t - t3) / ctd + 127.5;
    double b1  = (t + t3) / ctd + 127.5;
    double xlo = floor(fmin(b0, b1));
    double xhi = ceil (fmax(b0, b1));
    xlo = fmax(xlo, 0.0);
    xhi = fmin(xhi, 255.0);
    if (xlo > xhi) continue;
    int x0 = (int)xlo, x1 = (int)xhi;
    int xf = -1, xl = -2;
    for (int x = x0; x <= x1; ++x) {
      float xcv = __fsub_rn((float)x, 127.5f);
      float re  = __fadd_rn(__fmul_rn(xcv, ct), yst);   // mul-then-add, no FMA
      float d   = __fsub_rn(re, rp);
      if (fabsf(d) < mw) { if (xf < 0) xf = x; xl = x; }
    }
    if (xf < 0) continue;
    for (int w = xf >> 6; w <= (xl >> 6); ++w) {
      int lo = xf - (w << 6); lo = lo < 0 ? 0 : lo;
      int hi = xl - (w << 6); hi = hi > 63 ? 63 : hi;
      u64 m = (~0ull >> (63 - hi)) & (~0ull << lo);
      atomicOr(&rowbits[lr][w], m);
    }
  }
  __syncthreads();

  // bit -> float writeout, coalesced (each 256-iter chunk = one full row)
  for (int i = tid; i < RG * 256; i += 256) {
    int rr = i >> 8, c = i & 255;
    float v = (float)((rowbits[rr][c >> 6] >> (c & 63)) & 1ull);
    out[((size_t)nc * 256 + (size_t)(rg * RG + rr)) * 256 + c] = v;
  }
}

// ---------------------------------------------------------------------------
extern "C" void kernel_launch(void* const* d_in, const int* in_sizes, int n_in,
                              void* d_out, int out_size, void* d_ws, size_t ws_size,
                              hipStream_t stream) {
  const float* hm  = (const float*)d_in[0];   // [8,4,180,180] f32
  const float* mwp = (const float*)d_in[1];   // [1] f32
  const int*   Hp  = (const int*)d_in[2];     // [1] i32
  const int*   Wp  = (const int*)d_in[3];     // [1] i32
  float* out = (float*)d_out;                 // [8,4,256,256] f32

  char* base = (char*)d_ws;
  float* maxv = (float*)(base + OFF_MAX);
  u32*   cnt  = (u32*)(base + OFF_CNT);
  float* tbl  = (float*)(base + OFF_TBL);
  u32*   list = (u32*)(base + OFF_LIST);

  // zero only maxv+cnt (atomicAdd accumulates; must be deterministic per call)
  hipMemsetAsync(d_ws, 0, 256, stream);

  precompute_kernel<<<dim3(NC + 1), dim3(256), 0, stream>>>(hm, Hp, Wp, maxv, tbl);

  peaks_kernel<<<dim3((NC * AR + 255) / 256), dim3(256), 0, stream>>>(hm, maxv, cnt, list);

  raster_kernel<<<dim3(256 / RG, NC), dim3(256), 0, stream>>>(mwp, cnt, list, tbl, out);
}

// Round 4
// 82.834 us; speedup vs baseline: 4.1243x; 4.1243x over previous
//
#include <hip/hip_runtime.h>
#include <math.h>

// Problem dims (fixed by setup_inputs)
#define N_  8
#define C_  4
#define A_  180
#define R_  180
#define NC  (N_*C_)        // 32
#define AR  (A_*R_)        // 32400
#define CAP 2048           // max peaks per (n,c) — expected ~450
#define PS  16             // peak slices (blocks per nc in raster)

typedef unsigned long long u64;
typedef unsigned int u32;

// ws layout (bytes) — zeroed prefix = [0, OFF_TBL)
#define OFF_MAXV 0                       // u32 maxv[32] (encoded float keys)
#define OFF_CNT  128                     // u32 cnt[32*32] (one line per nc)
#define OFF_GM   4224                    // u64 gmask[32][1024] (256 KB)
#define OFF_TBL  266368                  // float ct[180] st[180] rp[180]
#define OFF_LIST 268544                  // u32 list[32][CAP] (256 KB)
#define ZERO_BYTES OFF_TBL

// monotone float <-> u32 key (for atomicMax on possibly-negative floats)
__device__ __forceinline__ u32 fkey(float f) {
  u32 b = __float_as_uint(f);
  return (b & 0x80000000u) ? ~b : (b | 0x80000000u);
}
__device__ __forceinline__ float fval(u32 k) {
  u32 b = (k & 0x80000000u) ? (k ^ 0x80000000u) : ~k;
  return __uint_as_float(b);
}

// ---------------------------------------------------------------------------
// Kernel A: per-(n,c) max via 8 partial blocks + atomicMax (no return);
// block (8,0) builds trig/rho tables.
// ---------------------------------------------------------------------------
__global__ __launch_bounds__(256) void maxtbl_kernel(
    const float* __restrict__ hm,
    const int* __restrict__ Hp, const int* __restrict__ Wp,
    u32* __restrict__ maxv, float* __restrict__ tbl) {
  int bx = blockIdx.x, nc = blockIdx.y;
  if (bx < 8) {
    const float4* p = (const float4*)(hm + (size_t)nc * AR);  // 8100 float4
    float m = -INFINITY;
    for (int i = bx * 256 + threadIdx.x; i < AR / 4; i += 8 * 256) {
      float4 v = p[i];
      m = fmaxf(fmaxf(m, fmaxf(v.x, v.y)), fmaxf(v.z, v.w));
    }
    for (int off = 32; off; off >>= 1) m = fmaxf(m, __shfl_down(m, off, 64));
    __shared__ float sm[4];
    if ((threadIdx.x & 63) == 0) sm[threadIdx.x >> 6] = m;
    __syncthreads();
    if (threadIdx.x == 0) {
      m = fmaxf(fmaxf(sm[0], sm[1]), fmaxf(sm[2], sm[3]));
      atomicMax(&maxv[nc], fkey(m));
    }
  } else if (nc == 0) {
    int t = threadIdx.x;
    int H = Hp[0], W = Wp[0];
    double max_rho = sqrt((double)(W/2)*(double)(W/2) + (double)(H/2)*(double)(H/2));
    float drho = (float)(2.0 * max_rho / (double)(R_ - 1));
    if (t < A_) {
      // theta = f32(a) * f32(pi/A)  — matches jnp.arange(A,f32)*(np.pi/A)
      float theta = __fmul_rn((float)t, (float)(3.14159265358979323846 / (double)A_));
      tbl[t]        = (float)cos((double)theta);   // correctly-rounded f32
      tbl[A_ + t]   = (float)sin((double)theta);
      // r_phys = (f32(r) - 89.5) * f32(delta_rho)
      tbl[2*A_ + t] = __fmul_rn(__fsub_rn((float)t, (float)((R_-1)*0.5)), drho);
    }
  }
}

// ---------------------------------------------------------------------------
// Kernel B: peak detect -> compact list; ONE atomicAdd per wave (aggregated),
// counters padded one per 128-B line. Grid (127, 32): a wave never straddles nc.
// peak := hm > 0.5*max AND no 3x3 neighbor strictly greater (== maxpool SAME)
// ---------------------------------------------------------------------------
__global__ __launch_bounds__(256) void peaks_kernel(
    const float* __restrict__ hm, const u32* __restrict__ maxv,
    u32* __restrict__ cnt, u32* __restrict__ list) {
  int nc  = blockIdx.y;
  int idx = blockIdx.x * 256 + threadIdx.x;   // index within nc
  bool peak = false;
  int a = 0, r = 0;
  if (idx < AR) {
    const float* base = hm + (size_t)nc * AR;
    float val = base[idx];
    float thr = 0.5f * fval(maxv[nc]);
    if (val > thr) {
      a = idx / R_; r = idx - a * R_;
      peak = true;
      for (int da = -1; da <= 1 && peak; ++da) {
        int aa = a + da;
        if (aa < 0 || aa >= A_) continue;     // SAME pad with -inf
        for (int dr = -1; dr <= 1; ++dr) {
          if (da == 0 && dr == 0) continue;
          int rr = r + dr;
          if (rr < 0 || rr >= R_) continue;
          if (base[aa * R_ + rr] > val) { peak = false; break; }
        }
      }
    }
  }
  u64 m = __ballot(peak);
  if (m) {
    int lane = threadIdx.x & 63;
    int leader = (int)__ffsll((long long)m) - 1;
    u32 base_slot = 0;
    if (lane == leader) base_slot = atomicAdd(&cnt[nc * 32], (u32)__popcll(m));
    base_slot = (u32)__shfl((int)base_slot, leader, 64);
    if (peak) {
      u32 slot = base_slot + (u32)__popcll(m & ((1ull << lane) - 1ull));
      if (slot < CAP) list[(size_t)nc * CAP + slot] = (u32)((a << 8) | r);
    }
  }
}

// ---------------------------------------------------------------------------
// Kernel C: per-peak row rasterization. Thread = image row. For fixed
// (peak,row), d(x) = f32(f32(xcv*ct)+yst) - rp is monotone in x (f32 rounding
// is monotone), so {x : |d|<mw} is one interval; find its edges with two
// binary searches using the EXACT f32 predicate (no margins, no f64).
// NOTE: search starts at s=256 so the "no element satisfies" answer (u=256)
// is reachable — starting at 128 caps the result at 255 and drops border
// pixels (R3 bug: absmax 1.0 at image-edge bands).
// ---------------------------------------------------------------------------
__global__ __launch_bounds__(256) void raster_kernel(
    const float* __restrict__ mwp,
    const u32* __restrict__ cntg, const u32* __restrict__ listg,
    const float* __restrict__ tbl,
    u64* __restrict__ gmask) {
  __shared__ u64 rowbits[4 * 256];          // [word][row], 8 KB
  __shared__ float sct[CAP / PS], sst[CAP / PS], srp[CAP / PS];
  int bx = blockIdx.x;                      // peak slice 0..PS-1
  int nc = blockIdx.y;
  int tid = threadIdx.x;                    // = row y

  int cnt = (int)cntg[nc * 32]; if (cnt > CAP) cnt = CAP;
  int nsl = (cnt > bx) ? (cnt - bx + PS - 1) / PS : 0;

  for (int i = tid; i < nsl; i += 256) {
    u32 pk = listg[(size_t)nc * CAP + bx + i * PS];
    int a = (int)(pk >> 8), r = (int)(pk & 255u);
    sct[i] = tbl[a]; sst[i] = tbl[A_ + a]; srp[i] = tbl[2 * A_ + r];
  }
  for (int i = tid; i < 4 * 256; i += 256) rowbits[i] = 0ull;
  __syncthreads();

  float mw  = mwp[0];
  float nmw = -mw;
  float ycv = __fsub_rn((float)tid, 127.5f);

  for (int i = 0; i < nsl; ++i) {
    float ct = sct[i], st = sst[i], rp = srp[i];
    float yst = __fmul_rn(ycv, st);
    bool neg = ct < 0.0f;                   // d decreasing in x -> flip coord
    int u1 = 0, u2 = 0;                     // first u with d>-mw / d>=mw
    #pragma unroll
    for (int s = 256; s; s >>= 1) {
      if (u1 + s <= 256) {
        int u = u1 + s - 1; int x = neg ? 255 - u : u;
        float d = __fsub_rn(__fadd_rn(__fmul_rn(__fsub_rn((float)x, 127.5f), ct), yst), rp);
        if (!(d > nmw)) u1 += s;
      }
      if (u2 + s <= 256) {
        int u = u2 + s - 1; int x = neg ? 255 - u : u;
        float d = __fsub_rn(__fadd_rn(__fmul_rn(__fsub_rn((float)x, 127.5f), ct), yst), rp);
        if (!(d >= mw)) u2 += s;
      }
    }
    if (u1 < u2) {                          // covered u in [u1,u2)
      int xlo = neg ? 256 - u2 : u1;
      int xhi = neg ? 255 - u1 : u2 - 1;
      for (int w = xlo >> 6; w <= (xhi >> 6); ++w) {
        int lo = xlo - (w << 6); lo = lo < 0 ? 0 : lo;
        int hi = xhi - (w << 6); hi = hi > 63 ? 63 : hi;
        u64 msk = (~0ull >> (63 - hi)) & (~0ull << lo);
        rowbits[w * 256 + tid] |= msk;      // row exclusively owned
      }
    }
  }
  __syncthreads();

  for (int i = tid; i < 4 * 256; i += 256) {
    int w = i >> 8, y = i & 255;
    u64 v = rowbits[w * 256 + y];
    if (v) atomicOr(&gmask[(size_t)nc * 1024 + y * 4 + w], v);  // no return
  }
}

// ---------------------------------------------------------------------------
// Kernel D: bitmask -> float image, float4 stores
// ---------------------------------------------------------------------------
__global__ __launch_bounds__(256) void writeout_kernel(
    const u64* __restrict__ gmask, float* __restrict__ out) {
  int i = blockIdx.x * 256 + threadIdx.x;   // float4 index
  int f = i * 4;                            // flat pixel index
  u64 w = gmask[f >> 6];
  int sh = f & 63;
  float4 v;
  v.x = (float)((w >> sh) & 1ull);
  v.y = (float)((w >> (sh + 1)) & 1ull);
  v.z = (float)((w >> (sh + 2)) & 1ull);
  v.w = (float)((w >> (sh + 3)) & 1ull);
  ((float4*)out)[i] = v;
}

// ---------------------------------------------------------------------------
extern "C" void kernel_launch(void* const* d_in, const int* in_sizes, int n_in,
                              void* d_out, int out_size, void* d_ws, size_t ws_size,
                              hipStream_t stream) {
  const float* hm  = (const float*)d_in[0];   // [8,4,180,180] f32
  const float* mwp = (const float*)d_in[1];   // [1] f32
  const int*   Hp  = (const int*)d_in[2];     // [1] i32
  const int*   Wp  = (const int*)d_in[3];     // [1] i32
  float* out = (float*)d_out;                 // [8,4,256,256] f32

  char* base = (char*)d_ws;
  u32*  maxv = (u32*)(base + OFF_MAXV);
  u32*  cnt  = (u32*)(base + OFF_CNT);
  u64*  gm   = (u64*)(base + OFF_GM);
  float* tbl = (float*)(base + OFF_TBL);
  u32*  list = (u32*)(base + OFF_LIST);

  // zero maxv + cnt + gmask (accumulated via atomics; deterministic per call)
  hipMemsetAsync(d_ws, 0, ZERO_BYTES, stream);

  maxtbl_kernel<<<dim3(9, NC), dim3(256), 0, stream>>>(hm, Hp, Wp, maxv, tbl);

  peaks_kernel<<<dim3((AR + 255) / 256, NC), dim3(256), 0, stream>>>(hm, maxv, cnt, list);

  raster_kernel<<<dim3(PS, NC), dim3(256), 0, stream>>>(mwp, cnt, list, tbl, gm);

  writeout_kernel<<<dim3(out_size / 1024), dim3(256), 0, stream>>>(gm, out);
}